// Round 1
// baseline (5906.050 us; speedup 1.0000x reference)
//
#include <hip/hip_runtime.h>

#define D 128

// ---------------------------------------------------------------------------
// zero-fill (h accumulator must start at 0; harness poisons ws with 0xAA)
// ---------------------------------------------------------------------------
__global__ __launch_bounds__(256) void zero_kernel(float4* __restrict__ p, int n4) {
    int i = blockIdx.x * 256 + threadIdx.x;
    if (i < n4) p[i] = make_float4(0.f, 0.f, 0.f, 0.f);
}

// ---------------------------------------------------------------------------
// out[r][j] = sum_k A[r][k] * W[j][k] + bias[j] (+ extra[r][j])
// A: [M,128]  W: [128,128] row-major  out: [M,128]
// Tile: 64 rows x 64 cols per block (gridDim.y = 2 col-halves), 256 threads,
// 4x4 microtile. K=128 fully staged in LDS.
// LDS: As_t[k][m] (A transposed, 32KB) + Ws[j][k] (32KB) = 64KB exactly
//   -> 2 blocks/CU, 8 waves/CU.
// Both arrays use a group-of-4 XOR swizzle on the fast index so that both the
// staging writes and the compute-phase b128 reads are bank-conflict-free
// without padding (pad would break 16B alignment / blow the 64KB budget).
// ---------------------------------------------------------------------------
template <bool ADD_EXTRA>
__global__ __launch_bounds__(256, 2) void gemm128(
    const float* __restrict__ A, const float* __restrict__ W,
    const float* __restrict__ bias, const float* __restrict__ extra,
    float* __restrict__ out, int M) {
    __shared__ float As[128 * 64];  // As_t[k][m], column-swizzled
    __shared__ float Ws[64 * 128];  // Ws[j][k],  k-swizzled
    const int t  = threadIdx.x;
    const int r0 = blockIdx.x * 64;
    const int nb = blockIdx.y * 64;

    // ---- stage W rows nb..nb+63: 8192 floats, 8 float4 per thread ----
#pragma unroll
    for (int i = 0; i < 8; ++i) {
        int idx = (i * 256 + t) * 4;
        int j   = idx >> 7;    // 0..63 local row of W
        int k   = idx & 127;   // k, multiple of 4
        float4 w = *(const float4*)(W + (nb + j) * D + k);
        int kg = (((k >> 2) ^ ((j >> 2) & 15)) << 2);
        *(float4*)(Ws + j * 128 + kg) = w;
    }
    // ---- stage A rows r0..r0+63 transposed: 8 float4 per thread ----
#pragma unroll
    for (int i = 0; i < 8; ++i) {
        int idx = (i * 256 + t) * 4;
        int m   = idx >> 7;    // 0..63 local row
        int k   = idx & 127;
        int r   = r0 + m;
        float4 a = (r < M) ? *(const float4*)(A + (size_t)r * D + k)
                           : make_float4(0.f, 0.f, 0.f, 0.f);
        const float* av = (const float*)&a;
#pragma unroll
        for (int j = 0; j < 4; ++j) {
            int kk  = k + j;   // k..k+3 share (kk>>2)
            int col = (((m >> 2) ^ ((kk >> 2) & 15)) << 2) | (m & 3);
            As[kk * 64 + col] = av[j];
        }
    }
    __syncthreads();

    const int tn = (t & 15) * 4;          // local col base (0..60)
    const int tm = ((t >> 4) & 15) * 4;   // local row base (0..60)
    float acc[4][4] = {{0.f}};

#pragma unroll
    for (int k = 0; k < 128; k += 4) {
        float4 a[4];  // a[j] = A rows tm..tm+3 at depth k+j
        float4 b[4];  // b[ni] = W row tn+ni, depths k..k+3
#pragma unroll
        for (int j = 0; j < 4; ++j) {
            int kk   = k + j;
            int acol = (((tm >> 2) ^ ((kk >> 2) & 15)) << 2);
            a[j] = *(const float4*)(As + kk * 64 + acol);
        }
        int kg = (((k >> 2) ^ (t & 15)) << 2);  // (tn+ni)>>2 == t&15 for ni<4
#pragma unroll
        for (int ni = 0; ni < 4; ++ni)
            b[ni] = *(const float4*)(Ws + (tn + ni) * 128 + kg);

        const float* af = (const float*)a;
        const float* bf = (const float*)b;
#pragma unroll
        for (int mi = 0; mi < 4; ++mi)
#pragma unroll
            for (int ni = 0; ni < 4; ++ni)
                acc[mi][ni] += af[0 * 4 + mi] * bf[ni * 4 + 0] +
                               af[1 * 4 + mi] * bf[ni * 4 + 1] +
                               af[2 * 4 + mi] * bf[ni * 4 + 2] +
                               af[3 * 4 + mi] * bf[ni * 4 + 3];
    }

    float4 bb = *(const float4*)(bias + nb + tn);
#pragma unroll
    for (int mi = 0; mi < 4; ++mi) {
        int r = r0 + tm + mi;
        if (r < M) {
            float4 o;
            o.x = acc[mi][0] + bb.x;
            o.y = acc[mi][1] + bb.y;
            o.z = acc[mi][2] + bb.z;
            o.w = acc[mi][3] + bb.w;
            size_t off = (size_t)r * D + nb + tn;
            if (ADD_EXTRA) {
                float4 e = *(const float4*)(extra + off);
                o.x += e.x; o.y += e.y; o.z += e.z; o.w += e.w;
            }
            *(float4*)(out + off) = o;
        }
    }
}

// ---------------------------------------------------------------------------
// h[dst[e]] += Wh[src[e]]  (per-edge row scatter-add)
// 32 lanes per edge, float4 per lane -> coalesced 512B gather per edge.
// ---------------------------------------------------------------------------
__global__ __launch_bounds__(256) void scatter_add(
    const float* __restrict__ Wh, const int* __restrict__ src,
    const int* __restrict__ dst, float* __restrict__ h, int E) {
    int tid = blockIdx.x * 256 + threadIdx.x;
    int e   = tid >> 5;
    int c   = (tid & 31) * 4;
    if (e < E) {
        int s = src[e];
        int d = dst[e];
        float4 v = *(const float4*)(Wh + (size_t)s * D + c);
        float* p = h + (size_t)d * D + c;
        atomicAdd(p + 0, v.x);
        atomicAdd(p + 1, v.y);
        atomicAdd(p + 2, v.z);
        atomicAdd(p + 3, v.w);
    }
}

extern "C" void kernel_launch(void* const* d_in, const int* in_sizes, int n_in,
                              void* d_out, int out_size, void* d_ws, size_t ws_size,
                              hipStream_t stream) {
    const float* feats  = (const float*)d_in[0];
    const float* W_chem = (const float*)d_in[1];
    const float* b_chem = (const float*)d_in[2];
    const float* W_elec = (const float*)d_in[3];
    const float* b_elec = (const float*)d_in[4];
    const float* W_out  = (const float*)d_in[5];
    const float* b_out  = (const float*)d_in[6];
    const int* src_chem = (const int*)d_in[7];
    const int* dst_chem = (const int*)d_in[8];
    const int* src_elec = (const int*)d_in[9];
    const int* dst_elec = (const int*)d_in[10];
    float* out = (float*)d_out;

    const int N = in_sizes[0] / D;  // 50000
    const int E = in_sizes[7];      // 500000

    // ws layout: [Wh_chem: N*D][h: N*D]  (51.2 MB)
    float* Wh_chem = (float*)d_ws;
    float* h       = Wh_chem + (size_t)N * D;

    // 1. h = 0
    int n4 = N * D / 4;
    zero_kernel<<<(n4 + 255) / 256, 256, 0, stream>>>((float4*)h, n4);

    // 2. projections: Wh_chem -> ws, Wh_elec -> d_out (reused as `extra` later)
    dim3 g((N + 63) / 64, 2);
    gemm128<false><<<g, 256, 0, stream>>>(feats, W_chem, b_chem, nullptr, Wh_chem, N);
    gemm128<false><<<g, 256, 0, stream>>>(feats, W_elec, b_elec, nullptr, out, N);

    // 3. scatter-aggregate both edge types into h
    int sblocks = (E * 32 + 255) / 256;
    scatter_add<<<sblocks, 256, 0, stream>>>(Wh_chem, src_chem, dst_chem, h, E);
    scatter_add<<<sblocks, 256, 0, stream>>>(out,     src_elec, dst_elec, h, E);

    // 4. out = h @ W_out.T + b_out + Wh_elec   (extra==out aliasing is safe:
    //    each thread reads its own element before writing it; A-input is h)
    gemm128<true><<<g, 256, 0, stream>>>(h, W_out, b_out, out, out, N);
}

// Round 2
// 5327.190 us; speedup vs baseline: 1.1087x; 1.1087x over previous
//
#include <hip/hip_runtime.h>

#define D 128

// ---------------------------------------------------------------------------
// zero-fill (h accumulator must start at 0; harness poisons ws with 0xAA)
// ---------------------------------------------------------------------------
__global__ __launch_bounds__(256) void zero_kernel(float4* __restrict__ p, int n4) {
    int i = blockIdx.x * 256 + threadIdx.x;
    if (i < n4) p[i] = make_float4(0.f, 0.f, 0.f, 0.f);
}

__device__ __forceinline__ void fma_row(float s, const float4 b, float4& acc) {
    acc.x = fmaf(s, b.x, acc.x);
    acc.y = fmaf(s, b.y, acc.y);
    acc.z = fmaf(s, b.z, acc.z);
    acc.w = fmaf(s, b.w, acc.w);
}

// ---------------------------------------------------------------------------
// out[r][j] = sum_k A[r][k] * W[j][k] + bias[j] (+ extra[r][j])
// A: [M,128]  W: [128,128] row-major  out: [M,128]
// 64x64 tile per block (gridDim.y = 2 col-halves), 256 threads, 4x4 microtile,
// K=128 fully staged in LDS (64 KB -> 2 blocks/CU).
// R1 fix: NO addressable locals (R0 spilled a[]/b[] to scratch via float* cast
// -> 3.3 GB HBM/dispatch, VALUBusy 1.6%). All fragments are explicit float4
// scalars with member access only.
// ---------------------------------------------------------------------------
template <bool ADD_EXTRA>
__global__ __launch_bounds__(256, 2) void gemm128(
    const float* __restrict__ A, const float* __restrict__ W,
    const float* __restrict__ bias, const float* __restrict__ extra,
    float* __restrict__ out, int M) {
    __shared__ float As[128 * 64];  // As_t[k][m], column-swizzled
    __shared__ float Ws[64 * 128];  // Ws[j][k],  k-swizzled
    const int t  = threadIdx.x;
    const int r0 = blockIdx.x * 64;
    const int nb = blockIdx.y * 64;

    // ---- stage W rows nb..nb+63: 8192 floats, 8 float4 per thread ----
#pragma unroll
    for (int i = 0; i < 8; ++i) {
        int idx = (i * 256 + t) * 4;
        int j   = idx >> 7;    // 0..63 local row of W
        int k   = idx & 127;   // k, multiple of 4
        float4 w = *(const float4*)(W + (nb + j) * D + k);
        int kg = (((k >> 2) ^ ((j >> 2) & 15)) << 2);
        *(float4*)(Ws + j * 128 + kg) = w;
    }
    // ---- stage A rows r0..r0+63 transposed: 8 float4 per thread ----
#pragma unroll
    for (int i = 0; i < 8; ++i) {
        int idx = (i * 256 + t) * 4;
        int m   = idx >> 7;    // 0..63 local row
        int k   = idx & 127;   // multiple of 4 -> (k+j)>>2 identical for j<4
        int r   = r0 + m;
        float4 a = (r < M) ? *(const float4*)(A + (size_t)r * D + k)
                           : make_float4(0.f, 0.f, 0.f, 0.f);
        int col = (((m >> 2) ^ ((k >> 2) & 15)) << 2) | (m & 3);
        As[(k + 0) * 64 + col] = a.x;
        As[(k + 1) * 64 + col] = a.y;
        As[(k + 2) * 64 + col] = a.z;
        As[(k + 3) * 64 + col] = a.w;
    }
    __syncthreads();

    const int tn = (t & 15) * 4;          // local col base (0..60)
    const int tm = ((t >> 4) & 15) * 4;   // local row base (0..60)
    float4 acc0 = make_float4(0.f, 0.f, 0.f, 0.f);  // row tm+0, cols tn..tn+3
    float4 acc1 = make_float4(0.f, 0.f, 0.f, 0.f);
    float4 acc2 = make_float4(0.f, 0.f, 0.f, 0.f);
    float4 acc3 = make_float4(0.f, 0.f, 0.f, 0.f);

#pragma unroll
    for (int k = 0; k < 128; k += 4) {
        // a_j = A rows tm..tm+3 (components) at depth k+j
        const int acol = (((tm >> 2) ^ ((k >> 2) & 15)) << 2);  // same for j<4
        float4 a0 = *(const float4*)(As + (k + 0) * 64 + acol);
        float4 a1 = *(const float4*)(As + (k + 1) * 64 + acol);
        float4 a2 = *(const float4*)(As + (k + 2) * 64 + acol);
        float4 a3 = *(const float4*)(As + (k + 3) * 64 + acol);
        // b_ni = W row tn+ni, depths k..k+3 (components)
        const int kg = (((k >> 2) ^ (t & 15)) << 2);  // (tn+ni)>>2 == t&15
        float4 b0 = *(const float4*)(Ws + (tn + 0) * 128 + kg);
        float4 b1 = *(const float4*)(Ws + (tn + 1) * 128 + kg);
        float4 b2 = *(const float4*)(Ws + (tn + 2) * 128 + kg);
        float4 b3 = *(const float4*)(Ws + (tn + 3) * 128 + kg);

        // depth k+0: bj = {b0.x, b1.x, b2.x, b3.x}, scalars from a0
        float4 bj;
        bj = make_float4(b0.x, b1.x, b2.x, b3.x);
        fma_row(a0.x, bj, acc0); fma_row(a0.y, bj, acc1);
        fma_row(a0.z, bj, acc2); fma_row(a0.w, bj, acc3);
        // depth k+1
        bj = make_float4(b0.y, b1.y, b2.y, b3.y);
        fma_row(a1.x, bj, acc0); fma_row(a1.y, bj, acc1);
        fma_row(a1.z, bj, acc2); fma_row(a1.w, bj, acc3);
        // depth k+2
        bj = make_float4(b0.z, b1.z, b2.z, b3.z);
        fma_row(a2.x, bj, acc0); fma_row(a2.y, bj, acc1);
        fma_row(a2.z, bj, acc2); fma_row(a2.w, bj, acc3);
        // depth k+3
        bj = make_float4(b0.w, b1.w, b2.w, b3.w);
        fma_row(a3.x, bj, acc0); fma_row(a3.y, bj, acc1);
        fma_row(a3.z, bj, acc2); fma_row(a3.w, bj, acc3);
    }

    float4 bb = *(const float4*)(bias + nb + tn);
#pragma unroll
    for (int mi = 0; mi < 4; ++mi) {
        int r = r0 + tm + mi;
        if (r < M) {
            float4 av = (mi == 0) ? acc0 : (mi == 1) ? acc1 : (mi == 2) ? acc2 : acc3;
            float4 o;
            o.x = av.x + bb.x;
            o.y = av.y + bb.y;
            o.z = av.z + bb.z;
            o.w = av.w + bb.w;
            size_t off = (size_t)r * D + nb + tn;
            if (ADD_EXTRA) {
                float4 e = *(const float4*)(extra + off);
                o.x += e.x; o.y += e.y; o.z += e.z; o.w += e.w;
            }
            *(float4*)(out + off) = o;
        }
    }
}

// ---------------------------------------------------------------------------
// h[dst[e]] += Wh[src[e]]  (per-edge row scatter-add)
// 32 lanes per edge, float4 per lane -> coalesced 512B gather per edge.
// ---------------------------------------------------------------------------
__global__ __launch_bounds__(256) void scatter_add(
    const float* __restrict__ Wh, const int* __restrict__ src,
    const int* __restrict__ dst, float* __restrict__ h, int E) {
    int tid = blockIdx.x * 256 + threadIdx.x;
    int e   = tid >> 5;
    int c   = (tid & 31) * 4;
    if (e < E) {
        int s = src[e];
        int d = dst[e];
        float4 v = *(const float4*)(Wh + (size_t)s * D + c);
        float* p = h + (size_t)d * D + c;
        atomicAdd(p + 0, v.x);
        atomicAdd(p + 1, v.y);
        atomicAdd(p + 2, v.z);
        atomicAdd(p + 3, v.w);
    }
}

extern "C" void kernel_launch(void* const* d_in, const int* in_sizes, int n_in,
                              void* d_out, int out_size, void* d_ws, size_t ws_size,
                              hipStream_t stream) {
    const float* feats  = (const float*)d_in[0];
    const float* W_chem = (const float*)d_in[1];
    const float* b_chem = (const float*)d_in[2];
    const float* W_elec = (const float*)d_in[3];
    const float* b_elec = (const float*)d_in[4];
    const float* W_out  = (const float*)d_in[5];
    const float* b_out  = (const float*)d_in[6];
    const int* src_chem = (const int*)d_in[7];
    const int* dst_chem = (const int*)d_in[8];
    const int* src_elec = (const int*)d_in[9];
    const int* dst_elec = (const int*)d_in[10];
    float* out = (float*)d_out;

    const int N = in_sizes[0] / D;  // 50000
    const int E = in_sizes[7];      // 500000

    // ws layout: [Wh_chem: N*D][h: N*D]  (51.2 MB)
    float* Wh_chem = (float*)d_ws;
    float* h       = Wh_chem + (size_t)N * D;

    // 1. h = 0
    int n4 = N * D / 4;
    zero_kernel<<<(n4 + 255) / 256, 256, 0, stream>>>((float4*)h, n4);

    // 2. projections: Wh_chem -> ws, Wh_elec -> d_out (reused as `extra` later)
    dim3 g((N + 63) / 64, 2);
    gemm128<false><<<g, 256, 0, stream>>>(feats, W_chem, b_chem, nullptr, Wh_chem, N);
    gemm128<false><<<g, 256, 0, stream>>>(feats, W_elec, b_elec, nullptr, out, N);

    // 3. scatter-aggregate both edge types into h
    int sblocks = (E * 32 + 255) / 256;
    scatter_add<<<sblocks, 256, 0, stream>>>(Wh_chem, src_chem, dst_chem, h, E);
    scatter_add<<<sblocks, 256, 0, stream>>>(out,     src_elec, dst_elec, h, E);

    // 4. out = h @ W_out.T + b_out + Wh_elec   (extra==out aliasing is safe:
    //    each thread reads its own element before writing it; A-input is h)
    gemm128<true><<<g, 256, 0, stream>>>(h, W_out, b_out, out, out, N);
}

// Round 4
// 1886.937 us; speedup vs baseline: 3.1300x; 2.8232x over previous
//
#include <hip/hip_runtime.h>

#define D 128

// ---------------------------------------------------------------------------
// zero-fill (h accumulator must start at 0; harness poisons ws with 0xAA)
// ---------------------------------------------------------------------------
__global__ __launch_bounds__(256) void zero_kernel(float4* __restrict__ p, int n4) {
    int i = blockIdx.x * 256 + threadIdx.x;
    if (i < n4) p[i] = make_float4(0.f, 0.f, 0.f, 0.f);
}

__device__ __forceinline__ void fma_row(float s, const float4 b, float4& acc) {
    acc.x = fmaf(s, b.x, acc.x);
    acc.y = fmaf(s, b.y, acc.y);
    acc.z = fmaf(s, b.z, acc.z);
    acc.w = fmaf(s, b.w, acc.w);
}

// ---------------------------------------------------------------------------
// out[r][j] = sum_k A[r][k] * W[j][k] + bias[j] (+ extra[r][j])
// A: [M,128]  W: [128,128] row-major  out: [M,128]
// 64x64 tile per block (gridDim.y = 2 col-halves), 256 threads, 4x4 microtile,
// K=128 fully staged in LDS (64 KB -> 2 blocks/CU).
// R2: K-loop ROLLED (#pragma unroll 2) — R0/R1's fully-unrolled ~20KB body let
// the scheduler hoist 256 ds_read_b128s past the register budget and spill
// ~3KB/thread to scratch (2.8GB HBM/dispatch, VALUBusy 1.7%).
// R3: `extra`/`out` are NOT __restrict__ — the final launch passes the same
// pointer for both (in-place add of Wh_elec); restrict there was UB.
// ---------------------------------------------------------------------------
template <bool ADD_EXTRA>
__global__ __launch_bounds__(256, 2) void gemm128(
    const float* __restrict__ A, const float* __restrict__ W,
    const float* __restrict__ bias, const float* extra,
    float* out, int M) {
    __shared__ float As[128 * 64];  // As_t[k][m], column-swizzled
    __shared__ float Ws[64 * 128];  // Ws[j][k],  k-swizzled
    const int t  = threadIdx.x;
    const int r0 = blockIdx.x * 64;
    const int nb = blockIdx.y * 64;

    // ---- stage W rows nb..nb+63: 8192 floats, 8 float4 per thread ----
#pragma unroll
    for (int i = 0; i < 8; ++i) {
        int idx = (i * 256 + t) * 4;
        int j   = idx >> 7;    // 0..63 local row of W
        int k   = idx & 127;   // k, multiple of 4
        float4 w = *(const float4*)(W + (nb + j) * D + k);
        int kg = (((k >> 2) ^ ((j >> 2) & 15)) << 2);
        *(float4*)(Ws + j * 128 + kg) = w;
    }
    // ---- stage A rows r0..r0+63 transposed: 8 float4 per thread ----
#pragma unroll
    for (int i = 0; i < 8; ++i) {
        int idx = (i * 256 + t) * 4;
        int m   = idx >> 7;    // 0..63 local row
        int k   = idx & 127;   // multiple of 4 -> (k+j)>>2 identical for j<4
        int r   = r0 + m;
        float4 a = (r < M) ? *(const float4*)(A + (size_t)r * D + k)
                           : make_float4(0.f, 0.f, 0.f, 0.f);
        int col = (((m >> 2) ^ ((k >> 2) & 15)) << 2) | (m & 3);
        As[(k + 0) * 64 + col] = a.x;
        As[(k + 1) * 64 + col] = a.y;
        As[(k + 2) * 64 + col] = a.z;
        As[(k + 3) * 64 + col] = a.w;
    }
    __syncthreads();

    const int tn = (t & 15) * 4;          // local col base (0..60)
    const int tm = ((t >> 4) & 15) * 4;   // local row base (0..60)
    float4 acc0 = make_float4(0.f, 0.f, 0.f, 0.f);  // row tm+0, cols tn..tn+3
    float4 acc1 = make_float4(0.f, 0.f, 0.f, 0.f);
    float4 acc2 = make_float4(0.f, 0.f, 0.f, 0.f);
    float4 acc3 = make_float4(0.f, 0.f, 0.f, 0.f);

    // ROLLED: small scheduling window, no scratch spill.
#pragma unroll 2
    for (int k = 0; k < 128; k += 4) {
        // a_j = A rows tm..tm+3 (components) at depth k+j
        const int acol = (((tm >> 2) ^ ((k >> 2) & 15)) << 2);  // same for j<4
        float4 a0 = *(const float4*)(As + (k + 0) * 64 + acol);
        float4 a1 = *(const float4*)(As + (k + 1) * 64 + acol);
        float4 a2 = *(const float4*)(As + (k + 2) * 64 + acol);
        float4 a3 = *(const float4*)(As + (k + 3) * 64 + acol);
        // b_ni = W row tn+ni, depths k..k+3 (components)
        const int kg = (((k >> 2) ^ (t & 15)) << 2);  // (tn+ni)>>2 == t&15
        float4 b0 = *(const float4*)(Ws + (tn + 0) * 128 + kg);
        float4 b1 = *(const float4*)(Ws + (tn + 1) * 128 + kg);
        float4 b2 = *(const float4*)(Ws + (tn + 2) * 128 + kg);
        float4 b3 = *(const float4*)(Ws + (tn + 3) * 128 + kg);

        float4 bj;
        bj = make_float4(b0.x, b1.x, b2.x, b3.x);
        fma_row(a0.x, bj, acc0); fma_row(a0.y, bj, acc1);
        fma_row(a0.z, bj, acc2); fma_row(a0.w, bj, acc3);
        bj = make_float4(b0.y, b1.y, b2.y, b3.y);
        fma_row(a1.x, bj, acc0); fma_row(a1.y, bj, acc1);
        fma_row(a1.z, bj, acc2); fma_row(a1.w, bj, acc3);
        bj = make_float4(b0.z, b1.z, b2.z, b3.z);
        fma_row(a2.x, bj, acc0); fma_row(a2.y, bj, acc1);
        fma_row(a2.z, bj, acc2); fma_row(a2.w, bj, acc3);
        bj = make_float4(b0.w, b1.w, b2.w, b3.w);
        fma_row(a3.x, bj, acc0); fma_row(a3.y, bj, acc1);
        fma_row(a3.z, bj, acc2); fma_row(a3.w, bj, acc3);
    }

    const float4 bb = *(const float4*)(bias + nb + tn);
    const size_t base = (size_t)(r0 + tm) * D + nb + tn;

    {   // row tm+0
        int r = r0 + tm + 0;
        if (r < M) {
            float4 o = make_float4(acc0.x + bb.x, acc0.y + bb.y, acc0.z + bb.z, acc0.w + bb.w);
            if (ADD_EXTRA) { float4 e = *(const float4*)(extra + base); o.x += e.x; o.y += e.y; o.z += e.z; o.w += e.w; }
            *(float4*)(out + base) = o;
        }
    }
    {   // row tm+1
        int r = r0 + tm + 1;
        if (r < M) {
            float4 o = make_float4(acc1.x + bb.x, acc1.y + bb.y, acc1.z + bb.z, acc1.w + bb.w);
            if (ADD_EXTRA) { float4 e = *(const float4*)(extra + base + D); o.x += e.x; o.y += e.y; o.z += e.z; o.w += e.w; }
            *(float4*)(out + base + D) = o;
        }
    }
    {   // row tm+2
        int r = r0 + tm + 2;
        if (r < M) {
            float4 o = make_float4(acc2.x + bb.x, acc2.y + bb.y, acc2.z + bb.z, acc2.w + bb.w);
            if (ADD_EXTRA) { float4 e = *(const float4*)(extra + base + 2 * D); o.x += e.x; o.y += e.y; o.z += e.z; o.w += e.w; }
            *(float4*)(out + base + 2 * D) = o;
        }
    }
    {   // row tm+3
        int r = r0 + tm + 3;
        if (r < M) {
            float4 o = make_float4(acc3.x + bb.x, acc3.y + bb.y, acc3.z + bb.z, acc3.w + bb.w);
            if (ADD_EXTRA) { float4 e = *(const float4*)(extra + base + 3 * D); o.x += e.x; o.y += e.y; o.z += e.z; o.w += e.w; }
            *(float4*)(out + base + 3 * D) = o;
        }
    }
}

// ---------------------------------------------------------------------------
// h[dst[e]] += Wh[src[e]]  (per-edge row scatter-add)
// 32 lanes per edge, float4 per lane -> coalesced 512B gather per edge.
// ---------------------------------------------------------------------------
__global__ __launch_bounds__(256) void scatter_add(
    const float* __restrict__ Wh, const int* __restrict__ src,
    const int* __restrict__ dst, float* __restrict__ h, int E) {
    int tid = blockIdx.x * 256 + threadIdx.x;
    int e   = tid >> 5;
    int c   = (tid & 31) * 4;
    if (e < E) {
        int s = src[e];
        int d = dst[e];
        float4 v = *(const float4*)(Wh + (size_t)s * D + c);
        float* p = h + (size_t)d * D + c;
        atomicAdd(p + 0, v.x);
        atomicAdd(p + 1, v.y);
        atomicAdd(p + 2, v.z);
        atomicAdd(p + 3, v.w);
    }
}

extern "C" void kernel_launch(void* const* d_in, const int* in_sizes, int n_in,
                              void* d_out, int out_size, void* d_ws, size_t ws_size,
                              hipStream_t stream) {
    const float* feats  = (const float*)d_in[0];
    const float* W_chem = (const float*)d_in[1];
    const float* b_chem = (const float*)d_in[2];
    const float* W_elec = (const float*)d_in[3];
    const float* b_elec = (const float*)d_in[4];
    const float* W_out  = (const float*)d_in[5];
    const float* b_out  = (const float*)d_in[6];
    const int* src_chem = (const int*)d_in[7];
    const int* dst_chem = (const int*)d_in[8];
    const int* src_elec = (const int*)d_in[9];
    const int* dst_elec = (const int*)d_in[10];
    float* out = (float*)d_out;

    const int N = in_sizes[0] / D;  // 50000
    const int E = in_sizes[7];      // 500000

    // ws layout: [Wh_chem: N*D][h: N*D]  (51.2 MB)
    float* Wh_chem = (float*)d_ws;
    float* h       = Wh_chem + (size_t)N * D;

    // 1. h = 0
    int n4 = N * D / 4;
    zero_kernel<<<(n4 + 255) / 256, 256, 0, stream>>>((float4*)h, n4);

    // 2. projections: Wh_chem -> ws, Wh_elec -> d_out (reused as `extra` later)
    dim3 g((N + 63) / 64, 2);
    gemm128<false><<<g, 256, 0, stream>>>(feats, W_chem, b_chem, nullptr, Wh_chem, N);
    gemm128<false><<<g, 256, 0, stream>>>(feats, W_elec, b_elec, nullptr, out, N);

    // 3. scatter-aggregate both edge types into h
    int sblocks = (E * 32 + 255) / 256;
    scatter_add<<<sblocks, 256, 0, stream>>>(Wh_chem, src_chem, dst_chem, h, E);
    scatter_add<<<sblocks, 256, 0, stream>>>(out,     src_elec, dst_elec, h, E);

    // 4. out = h @ W_out.T + b_out + Wh_elec  (extra==out; both non-restrict,
    //    each thread reads its element before writing it; A-input is h)
    gemm128<true><<<g, 256, 0, stream>>>(h, W_out, b_out, out, out, N);
}

// Round 5
// 467.807 us; speedup vs baseline: 12.6250x; 4.0336x over previous
//
#include <hip/hip_runtime.h>

#define D 128

// ============================ small utilities ==============================

__global__ __launch_bounds__(256) void zero_ints(int* __restrict__ p, int n) {
    int i = blockIdx.x * 256 + threadIdx.x;
    if (i < n) p[i] = 0;
}

// c[dst[e]] += 1
__global__ __launch_bounds__(256) void hist_kernel(const int* __restrict__ dst,
                                                   int* __restrict__ c, int E) {
    int e = blockIdx.x * 256 + threadIdx.x;
    if (e < E) atomicAdd(&c[dst[e]], 1);
}

// per-block exclusive scan of c -> row_ptr, block totals -> aux
__global__ __launch_bounds__(256) void scan_block(const int* __restrict__ c,
                                                  int* __restrict__ row_ptr,
                                                  int* __restrict__ aux, int n) {
    __shared__ int sd[256];
    const int t = threadIdx.x;
    const int i = blockIdx.x * 256 + t;
    int x = (i < n) ? c[i] : 0;
    sd[t] = x;
    __syncthreads();
#pragma unroll
    for (int off = 1; off < 256; off <<= 1) {
        int y = (t >= off) ? sd[t - off] : 0;
        __syncthreads();
        sd[t] += y;
        __syncthreads();
    }
    if (i < n) row_ptr[i] = sd[t] - x;  // exclusive
    if (t == 255) aux[blockIdx.x] = sd[255];
}

// exclusive scan of aux in place (nb <= 256), single block
__global__ __launch_bounds__(256) void scan_aux(int* __restrict__ aux, int nb) {
    __shared__ int sd[256];
    const int t = threadIdx.x;
    int x = (t < nb) ? aux[t] : 0;
    sd[t] = x;
    __syncthreads();
#pragma unroll
    for (int off = 1; off < 256; off <<= 1) {
        int y = (t >= off) ? sd[t - off] : 0;
        __syncthreads();
        sd[t] += y;
        __syncthreads();
    }
    if (t < nb) aux[t] = sd[t] - x;
}

// row_ptr[i] += aux[block]; thread at i==n-1 also writes row_ptr[n] = E
__global__ __launch_bounds__(256) void scan_add(int* __restrict__ row_ptr,
                                                const int* __restrict__ aux,
                                                const int* __restrict__ c, int n) {
    int i = blockIdx.x * 256 + threadIdx.x;
    if (i < n) {
        int r = row_ptr[i] + aux[blockIdx.x];
        row_ptr[i] = r;
        if (i == n - 1) row_ptr[n] = r + c[i];
    }
}

// csr[row_ptr[dst[e]] + pos] = src[e]   (pos via per-node cursor)
__global__ __launch_bounds__(256) void fill_csr(const int* __restrict__ src,
                                                const int* __restrict__ dst,
                                                const int* __restrict__ row_ptr,
                                                int* __restrict__ cursor,
                                                unsigned short* __restrict__ csr, int E) {
    int e = blockIdx.x * 256 + threadIdx.x;
    if (e < E) {
        int d   = dst[e];
        int pos = atomicAdd(&cursor[d], 1);
        csr[row_ptr[d] + pos] = (unsigned short)src[e];
    }
}

// S[v] = sum over in-edges of feats[src]  — one wave per node, float2/lane.
__global__ __launch_bounds__(256) void aggregate(const float* __restrict__ feats,
                                                 const unsigned short* __restrict__ csr,
                                                 const int* __restrict__ row_ptr,
                                                 float* __restrict__ S, int N) {
    const int v    = blockIdx.x * 4 + (threadIdx.x >> 6);
    const int lane = threadIdx.x & 63;
    if (v < N) {
        const int beg = row_ptr[v];
        const int end = row_ptr[v + 1];
        float sx = 0.f, sy = 0.f;
        for (int e = beg; e < end; ++e) {
            int sv = csr[e];
            const float2 f = *(const float2*)(feats + (size_t)sv * D + lane * 2);
            sx += f.x;
            sy += f.y;
        }
        float2 o; o.x = sx; o.y = sy;
        *(float2*)(S + (size_t)v * D + lane * 2) = o;
    }
}

// ============================ GEMM =========================================

__device__ __forceinline__ void fma_row(float s, const float4 b, float4& acc) {
    acc.x = fmaf(s, b.x, acc.x);
    acc.y = fmaf(s, b.y, acc.y);
    acc.z = fmaf(s, b.z, acc.z);
    acc.w = fmaf(s, b.w, acc.w);
}

// out[r][j] = sum_k A[r][k]*W[j][k] + degscale(r)*bias[j] (+ extra[r][j])
// 64x64 tile/block (gridDim.y=2), 256 threads, 4x4 microtile, K=128 in LDS.
// K-loop ROLLED (unroll 2): full unroll made the scheduler hoist 256
// ds_read_b128s -> ~3KB/thread scratch spill (R0/R1: 2.8GB HBM, VALUBusy 1.7%).
// extra/out NOT __restrict__: callers pass extra==out (in-place accumulate;
// each thread reads its element before writing it — safe, A never aliases out).
template <bool ADD_EXTRA, bool DEG_BIAS>
__global__ __launch_bounds__(256, 2) void gemm128(
    const float* __restrict__ A, const float* __restrict__ W,
    const float* __restrict__ bias, const int* __restrict__ deg,
    const float* extra, float* out, int M) {
    __shared__ float As[128 * 64];  // As_t[k][m], column-swizzled
    __shared__ float Ws[64 * 128];  // Ws[j][k],  k-swizzled
    const int t  = threadIdx.x;
    const int r0 = blockIdx.x * 64;
    const int nb = blockIdx.y * 64;

#pragma unroll
    for (int i = 0; i < 8; ++i) {
        int idx = (i * 256 + t) * 4;
        int j   = idx >> 7;
        int k   = idx & 127;
        float4 w = *(const float4*)(W + (nb + j) * D + k);
        int kg = (((k >> 2) ^ ((j >> 2) & 15)) << 2);
        *(float4*)(Ws + j * 128 + kg) = w;
    }
#pragma unroll
    for (int i = 0; i < 8; ++i) {
        int idx = (i * 256 + t) * 4;
        int m   = idx >> 7;
        int k   = idx & 127;
        int r   = r0 + m;
        float4 a = (r < M) ? *(const float4*)(A + (size_t)r * D + k)
                           : make_float4(0.f, 0.f, 0.f, 0.f);
        int col = (((m >> 2) ^ ((k >> 2) & 15)) << 2) | (m & 3);
        As[(k + 0) * 64 + col] = a.x;
        As[(k + 1) * 64 + col] = a.y;
        As[(k + 2) * 64 + col] = a.z;
        As[(k + 3) * 64 + col] = a.w;
    }
    __syncthreads();

    const int tn = (t & 15) * 4;
    const int tm = ((t >> 4) & 15) * 4;
    float4 acc0 = make_float4(0.f, 0.f, 0.f, 0.f);
    float4 acc1 = make_float4(0.f, 0.f, 0.f, 0.f);
    float4 acc2 = make_float4(0.f, 0.f, 0.f, 0.f);
    float4 acc3 = make_float4(0.f, 0.f, 0.f, 0.f);

#pragma unroll 2
    for (int k = 0; k < 128; k += 4) {
        const int acol = (((tm >> 2) ^ ((k >> 2) & 15)) << 2);
        float4 a0 = *(const float4*)(As + (k + 0) * 64 + acol);
        float4 a1 = *(const float4*)(As + (k + 1) * 64 + acol);
        float4 a2 = *(const float4*)(As + (k + 2) * 64 + acol);
        float4 a3 = *(const float4*)(As + (k + 3) * 64 + acol);
        const int kg = (((k >> 2) ^ (t & 15)) << 2);
        float4 b0 = *(const float4*)(Ws + (tn + 0) * 128 + kg);
        float4 b1 = *(const float4*)(Ws + (tn + 1) * 128 + kg);
        float4 b2 = *(const float4*)(Ws + (tn + 2) * 128 + kg);
        float4 b3 = *(const float4*)(Ws + (tn + 3) * 128 + kg);

        float4 bj;
        bj = make_float4(b0.x, b1.x, b2.x, b3.x);
        fma_row(a0.x, bj, acc0); fma_row(a0.y, bj, acc1);
        fma_row(a0.z, bj, acc2); fma_row(a0.w, bj, acc3);
        bj = make_float4(b0.y, b1.y, b2.y, b3.y);
        fma_row(a1.x, bj, acc0); fma_row(a1.y, bj, acc1);
        fma_row(a1.z, bj, acc2); fma_row(a1.w, bj, acc3);
        bj = make_float4(b0.z, b1.z, b2.z, b3.z);
        fma_row(a2.x, bj, acc0); fma_row(a2.y, bj, acc1);
        fma_row(a2.z, bj, acc2); fma_row(a2.w, bj, acc3);
        bj = make_float4(b0.w, b1.w, b2.w, b3.w);
        fma_row(a3.x, bj, acc0); fma_row(a3.y, bj, acc1);
        fma_row(a3.z, bj, acc2); fma_row(a3.w, bj, acc3);
    }

    const float4 bb = *(const float4*)(bias + nb + tn);
    const size_t base = (size_t)(r0 + tm) * D + nb + tn;

#define EPILOG_ROW(MI, ACC)                                                         \
    {                                                                               \
        int r = r0 + tm + MI;                                                       \
        if (r < M) {                                                                \
            float ds = DEG_BIAS ? (float)deg[r] : 1.0f;                             \
            float4 o;                                                               \
            o.x = fmaf(ds, bb.x, ACC.x);                                            \
            o.y = fmaf(ds, bb.y, ACC.y);                                            \
            o.z = fmaf(ds, bb.z, ACC.z);                                            \
            o.w = fmaf(ds, bb.w, ACC.w);                                            \
            if (ADD_EXTRA) {                                                        \
                float4 e = *(const float4*)(extra + base + MI * D);                 \
                o.x += e.x; o.y += e.y; o.z += e.z; o.w += e.w;                     \
            }                                                                       \
            *(float4*)(out + base + MI * D) = o;                                    \
        }                                                                           \
    }
    EPILOG_ROW(0, acc0)
    EPILOG_ROW(1, acc1)
    EPILOG_ROW(2, acc2)
    EPILOG_ROW(3, acc3)
#undef EPILOG_ROW
}

// ============================ driver =======================================
//
// Math refactor (linearity of segment_sum):
//   segsum(feats@W.T + b) = segsum(feats)@W.T + deg*b
// so:
//   S_c = pull-aggregate(feats, CSR_chem);  h  = S_c@Wc.T + deg_c*b_c
//   S_e = pull-aggregate(feats, CSR_elec);  h += S_e@We.T + deg_e*b_e
//   out = h@Wo.T + b_o;  out += feats@We.T + b_e     (the +Wh_elec term)
// Wh_elec is never materialized; S lives in d_out (free until the end);
// h + CSR live in ws (~27 MB, well under the proven 51.2 MB budget).
// Zero float atomics (only ~1M int atomics for CSR build).

extern "C" void kernel_launch(void* const* d_in, const int* in_sizes, int n_in,
                              void* d_out, int out_size, void* d_ws, size_t ws_size,
                              hipStream_t stream) {
    const float* feats  = (const float*)d_in[0];
    const float* W_chem = (const float*)d_in[1];
    const float* b_chem = (const float*)d_in[2];
    const float* W_elec = (const float*)d_in[3];
    const float* b_elec = (const float*)d_in[4];
    const float* W_out  = (const float*)d_in[5];
    const float* b_out  = (const float*)d_in[6];
    const int* src_chem = (const int*)d_in[7];
    const int* dst_chem = (const int*)d_in[8];
    const int* src_elec = (const int*)d_in[9];
    const int* dst_elec = (const int*)d_in[10];
    float* out = (float*)d_out;

    const int N = in_sizes[0] / D;  // 50000
    const int E = in_sizes[7];      // 500000

    // ws layout (4-byte units from base):
    float* h = (float*)d_ws;                                   // N*D floats
    int* c        = (int*)d_ws + (size_t)N * D;                // N ints (degree)
    int* cursor   = c + N;                                     // N ints
    int* row_ptr  = cursor + N;                                // N+1 ints (pad 16)
    int* aux      = row_ptr + N + 15;                          // 256 ints
    unsigned short* csr = (unsigned short*)(aux + 256);        // E u16

    float* S = out;  // aggregation target lives in d_out until the final GEMMs

    const int nscan = (N + 255) / 256;          // 196
    const int nedge = (E + 255) / 256;          // 1954
    const int nagg  = (N + 3) / 4;              // 12500
    dim3 g((N + 63) / 64, 2);                   // GEMM grid

    for (int et = 0; et < 2; ++et) {
        const int* src = et ? src_elec : src_chem;
        const int* dst = et ? dst_elec : dst_chem;
        // CSR build
        zero_ints<<<(2 * N + 255) / 256, 256, 0, stream>>>(c, 2 * N);  // c + cursor
        hist_kernel<<<nedge, 256, 0, stream>>>(dst, c, E);
        scan_block<<<nscan, 256, 0, stream>>>(c, row_ptr, aux, N);
        scan_aux<<<1, 256, 0, stream>>>(aux, nscan);
        scan_add<<<nscan, 256, 0, stream>>>(row_ptr, aux, c, N);
        fill_csr<<<nedge, 256, 0, stream>>>(src, dst, row_ptr, cursor, csr, E);
        // pull-aggregate raw feats
        aggregate<<<nagg, 256, 0, stream>>>(feats, csr, row_ptr, S, N);
        // project with degree-scaled bias; second etype accumulates into h
        if (et == 0)
            gemm128<false, true><<<g, 256, 0, stream>>>(S, W_chem, b_chem, c, nullptr, h, N);
        else
            gemm128<true, true><<<g, 256, 0, stream>>>(S, W_elec, b_elec, c, h, h, N);
    }

    // out = h@Wo.T + b_o ;  out += feats@We.T + b_e   (the +Wh_elec quirk term)
    gemm128<false, false><<<g, 256, 0, stream>>>(h, W_out, b_out, nullptr, nullptr, out, N);
    gemm128<true,  false><<<g, 256, 0, stream>>>(feats, W_elec, b_elec, nullptr, out, out, N);
}

// Round 6
// 360.996 us; speedup vs baseline: 16.3604x; 1.2959x over previous
//
#include <hip/hip_runtime.h>

#define D 128

typedef __attribute__((ext_vector_type(8))) short bf16x8;   // 8 bf16 in 4 VGPRs
typedef __attribute__((ext_vector_type(4))) float f32x4;

__device__ __forceinline__ unsigned short f2bf(float x) {
    unsigned int u = __float_as_uint(x);
    u += 0x7fffu + ((u >> 16) & 1u);   // round-to-nearest-even
    return (unsigned short)(u >> 16);
}
__device__ __forceinline__ unsigned int pk2(float lo, float hi) {
    return ((unsigned int)f2bf(hi) << 16) | (unsigned int)f2bf(lo);
}

// ============================ small utilities ==============================

__global__ __launch_bounds__(256) void zero_ints(int* __restrict__ p, int n) {
    int i = blockIdx.x * 256 + threadIdx.x;
    if (i < n) p[i] = 0;
}

// feats fp32 -> bf16 (8 elems/thread)
__global__ __launch_bounds__(256) void convert_bf(const float4* __restrict__ f,
                                                  uint4* __restrict__ o, int n8) {
    int i = blockIdx.x * 256 + threadIdx.x;
    if (i < n8) {
        float4 a = f[2 * i];
        float4 b = f[2 * i + 1];
        o[i] = make_uint4(pk2(a.x, a.y), pk2(a.z, a.w), pk2(b.x, b.y), pk2(b.z, b.w));
    }
}

// c[dst[e]] += 1
__global__ __launch_bounds__(256) void hist_kernel(const int* __restrict__ dst,
                                                   int* __restrict__ c, int E) {
    int e = blockIdx.x * 256 + threadIdx.x;
    if (e < E) atomicAdd(&c[dst[e]], 1);
}

// per-block exclusive scan of c -> row_ptr, block totals -> aux
__global__ __launch_bounds__(256) void scan_block(const int* __restrict__ c,
                                                  int* __restrict__ row_ptr,
                                                  int* __restrict__ aux, int n) {
    __shared__ int sd[256];
    const int t = threadIdx.x;
    const int i = blockIdx.x * 256 + t;
    int x = (i < n) ? c[i] : 0;
    sd[t] = x;
    __syncthreads();
#pragma unroll
    for (int off = 1; off < 256; off <<= 1) {
        int y = (t >= off) ? sd[t - off] : 0;
        __syncthreads();
        sd[t] += y;
        __syncthreads();
    }
    if (i < n) row_ptr[i] = sd[t] - x;  // exclusive
    if (t == 255) aux[blockIdx.x] = sd[255];
}

__global__ __launch_bounds__(256) void scan_aux(int* __restrict__ aux, int nb) {
    __shared__ int sd[256];
    const int t = threadIdx.x;
    int x = (t < nb) ? aux[t] : 0;
    sd[t] = x;
    __syncthreads();
#pragma unroll
    for (int off = 1; off < 256; off <<= 1) {
        int y = (t >= off) ? sd[t - off] : 0;
        __syncthreads();
        sd[t] += y;
        __syncthreads();
    }
    if (t < nb) aux[t] = sd[t] - x;
}

__global__ __launch_bounds__(256) void scan_add(int* __restrict__ row_ptr,
                                                const int* __restrict__ aux,
                                                const int* __restrict__ c, int n) {
    int i = blockIdx.x * 256 + threadIdx.x;
    if (i < n) {
        int r = row_ptr[i] + aux[blockIdx.x];
        row_ptr[i] = r;
        if (i == n - 1) row_ptr[n] = r + c[i];
    }
}

// csr[row_ptr[dst[e]] + pos] = src[e]   (N < 65536 -> u16 ids)
__global__ __launch_bounds__(256) void fill_csr(const int* __restrict__ src,
                                                const int* __restrict__ dst,
                                                const int* __restrict__ row_ptr,
                                                int* __restrict__ cursor,
                                                unsigned short* __restrict__ csr, int E) {
    int e = blockIdx.x * 256 + threadIdx.x;
    if (e < E) {
        int d   = dst[e];
        int pos = atomicAdd(&cursor[d], 1);
        csr[row_ptr[d] + pos] = (unsigned short)src[e];
    }
}

// S[v] = sum of bf16 feats rows over in-edges; fp32 accumulate, bf16 store.
// One wave per node, 4 B (2 bf16) per lane -> 256 B coalesced gather per edge.
__global__ __launch_bounds__(256) void aggregate_bf(const unsigned short* __restrict__ fbf,
                                                    const unsigned short* __restrict__ csr,
                                                    const int* __restrict__ row_ptr,
                                                    unsigned short* __restrict__ S, int N) {
    const int v    = blockIdx.x * 4 + (threadIdx.x >> 6);
    const int lane = threadIdx.x & 63;
    if (v < N) {
        const int beg = row_ptr[v];
        const int end = row_ptr[v + 1];
        float sx = 0.f, sy = 0.f;
        for (int e = beg; e < end; ++e) {
            int sv = csr[e];
            unsigned int u = *(const unsigned int*)(fbf + (size_t)sv * D + lane * 2);
            sx += __uint_as_float(u << 16);
            sy += __uint_as_float(u & 0xffff0000u);
        }
        *(unsigned int*)(S + (size_t)v * D + lane * 2) =
            ((unsigned int)f2bf(sy) << 16) | (unsigned int)f2bf(sx);
    }
}

// ============================ MFMA dual GEMM ===============================
// out[r][j] = sum_k A1[r][k]*W1[j][k] + sum_k A2[r][k]*W2[j][k] + bias(r,j)
// A1,A2: bf16 [M,128]; W1,W2: fp32 [128,128] (converted to bf16 while staging).
// Block: 256 thr = 4 waves; BM=128, BN=64 (gridDim.y=2), K=2x128.
// LDS: Wt[64][256] bf16 (32KB, both W halves) + At[128][128] bf16 (32KB,
// restaged per half) = 64KB -> 2 blocks/CU. Chunk-XOR swizzle (16B chunks,
// chunk ^= row&7) makes all frag ds_read_b128s 2-way (free, m136).
// MFMA v_mfma_f32_16x16x32_bf16: A[m=lane&15][k=quad*8+j],
// B[n=lane&15][k=quad*8+j], C/D col=lane&15,row=quad*4+reg (m89/m91-verified).
template <bool DEG, bool OUT_BF16>
__global__ __launch_bounds__(256, 2) void gemm_dual(
    const unsigned short* __restrict__ A1, const unsigned short* __restrict__ A2,
    const float* __restrict__ W1, const float* __restrict__ W2,
    const float* __restrict__ bias1, const float* __restrict__ bias2,
    const int* __restrict__ deg1, const int* __restrict__ deg2,
    void* outp, int M) {
    __shared__ unsigned int Wt[64 * 128];   // 64 n-rows x 256 k (bf16 pairs)
    __shared__ unsigned int At[128 * 64];   // 128 m-rows x 128 k (bf16 pairs)
    const int t  = threadIdx.x;
    const int r0 = blockIdx.x * 128;
    const int nb = blockIdx.y * 64;

    // ---- stage W (both halves), fp32->bf16 on the fly ----
#pragma unroll
    for (int i = 0; i < 8; ++i) {
        int g  = i * 256 + t;
        int j  = g >> 5;      // 0..63 local n
        int cc = g & 31;      // 16B chunk (8 bf16), k = cc*8 over 0..255
        int k  = cc * 8;
        const float* row = (k < 128) ? (W1 + (nb + j) * 128 + k)
                                     : (W2 + (nb + j) * 128 + (k - 128));
        float4 w0 = *(const float4*)(row);
        float4 w1 = *(const float4*)(row + 4);
        *(uint4*)(Wt + j * 128 + ((cc ^ (j & 7)) << 2)) =
            make_uint4(pk2(w0.x, w0.y), pk2(w0.z, w0.w), pk2(w1.x, w1.y), pk2(w1.z, w1.w));
    }
    // ---- stage A half (bf16 source) ----
#define STAGE_A(AB)                                                             \
    {                                                                           \
        _Pragma("unroll") for (int i = 0; i < 8; ++i) {                         \
            int g  = i * 256 + t;                                               \
            int m  = g >> 4;                                                    \
            int cc = g & 15;                                                    \
            int r  = r0 + m;                                                    \
            uint4 v = make_uint4(0u, 0u, 0u, 0u);                               \
            if (r < M) v = *(const uint4*)((AB) + (size_t)r * 128 + cc * 8);    \
            *(uint4*)(At + m * 64 + ((cc ^ (m & 7)) << 2)) = v;                 \
        }                                                                       \
    }

    const int w    = t >> 6;
    const int w32  = w * 32;
    const int lane = t & 63;
    const int ln   = lane & 15;
    const int quad = lane >> 4;
    const int lnx  = ln & 7;
    const int rowA0 = (w32 + ln) * 64;
    const int rowA1 = (w32 + 16 + ln) * 64;
    const int rowB0 = (ln) * 128;
    const int rowB1 = (16 + ln) * 128;
    const int rowB2 = (32 + ln) * 128;
    const int rowB3 = (48 + ln) * 128;

    f32x4 acc00 = {0.f, 0.f, 0.f, 0.f}, acc01 = {0.f, 0.f, 0.f, 0.f};
    f32x4 acc02 = {0.f, 0.f, 0.f, 0.f}, acc03 = {0.f, 0.f, 0.f, 0.f};
    f32x4 acc10 = {0.f, 0.f, 0.f, 0.f}, acc11 = {0.f, 0.f, 0.f, 0.f};
    f32x4 acc12 = {0.f, 0.f, 0.f, 0.f}, acc13 = {0.f, 0.f, 0.f, 0.f};

#define KSTEP(KS, HC)                                                                \
    {                                                                                \
        const int ca = ((((KS)*4 + quad) ^ lnx) << 2);                               \
        bf16x8 a0 = *(const bf16x8*)(At + rowA0 + ca);                               \
        bf16x8 a1 = *(const bf16x8*)(At + rowA1 + ca);                               \
        const int cb = ((((HC) + (KS)*4 + quad) ^ lnx) << 2);                        \
        bf16x8 b0v = *(const bf16x8*)(Wt + rowB0 + cb);                              \
        bf16x8 b1v = *(const bf16x8*)(Wt + rowB1 + cb);                              \
        bf16x8 b2v = *(const bf16x8*)(Wt + rowB2 + cb);                              \
        bf16x8 b3v = *(const bf16x8*)(Wt + rowB3 + cb);                              \
        acc00 = __builtin_amdgcn_mfma_f32_16x16x32_bf16(a0, b0v, acc00, 0, 0, 0);    \
        acc01 = __builtin_amdgcn_mfma_f32_16x16x32_bf16(a0, b1v, acc01, 0, 0, 0);    \
        acc02 = __builtin_amdgcn_mfma_f32_16x16x32_bf16(a0, b2v, acc02, 0, 0, 0);    \
        acc03 = __builtin_amdgcn_mfma_f32_16x16x32_bf16(a0, b3v, acc03, 0, 0, 0);    \
        acc10 = __builtin_amdgcn_mfma_f32_16x16x32_bf16(a1, b0v, acc10, 0, 0, 0);    \
        acc11 = __builtin_amdgcn_mfma_f32_16x16x32_bf16(a1, b1v, acc11, 0, 0, 0);    \
        acc12 = __builtin_amdgcn_mfma_f32_16x16x32_bf16(a1, b2v, acc12, 0, 0, 0);    \
        acc13 = __builtin_amdgcn_mfma_f32_16x16x32_bf16(a1, b3v, acc13, 0, 0, 0);    \
    }

    STAGE_A(A1);
    __syncthreads();
    KSTEP(0, 0) KSTEP(1, 0) KSTEP(2, 0) KSTEP(3, 0)
    __syncthreads();
    STAGE_A(A2);
    __syncthreads();
    KSTEP(0, 16) KSTEP(1, 16) KSTEP(2, 16) KSTEP(3, 16)

    // ---- epilogue: C/D layout col=lane&15, row=quad*4+reg ----
#define EPI(ACC, MT, NI)                                                            \
    {                                                                               \
        const int col = nb + (NI)*16 + ln;                                          \
        float bc, be;                                                               \
        if (DEG) { bc = bias1[col]; be = bias2[col]; }                              \
        else     { bc = bias1[col] + bias2[col]; be = 0.f; }                        \
        _Pragma("unroll") for (int rg = 0; rg < 4; ++rg) {                          \
            const int rr = r0 + w32 + (MT)*16 + quad * 4 + rg;                      \
            if (rr < M) {                                                           \
                float val = ACC[rg];                                                \
                if (DEG) val += (float)deg1[rr] * bc + (float)deg2[rr] * be;        \
                else     val += bc;                                                 \
                if (OUT_BF16)                                                       \
                    ((unsigned short*)outp)[(size_t)rr * 128 + col] = f2bf(val);    \
                else                                                                \
                    ((float*)outp)[(size_t)rr * 128 + col] = val;                   \
            }                                                                       \
        }                                                                           \
    }
    EPI(acc00, 0, 0) EPI(acc01, 0, 1) EPI(acc02, 0, 2) EPI(acc03, 0, 3)
    EPI(acc10, 1, 0) EPI(acc11, 1, 1) EPI(acc12, 1, 2) EPI(acc13, 1, 3)
#undef EPI
#undef KSTEP
#undef STAGE_A
}

// ============================ driver =======================================
// segsum(feats@W.T + b) = segsum(feats)@W.T + deg*b  (linearity), so:
//   S_c = pull-agg(fbf, CSR_c);  S_e = pull-agg(fbf, CSR_e)      [bf16, d_out]
//   h   = S_c@Wc.T + S_e@We.T + deg_c*b_c + deg_e*b_e            [bf16, ws]
//   out = h@Wo.T + fbf@We.T + (b_o + b_e)                        [fp32, d_out]
// Zero float atomics; MFMA for all matmul FLOPs; ws ~27.5 MB.

extern "C" void kernel_launch(void* const* d_in, const int* in_sizes, int n_in,
                              void* d_out, int out_size, void* d_ws, size_t ws_size,
                              hipStream_t stream) {
    const float* feats  = (const float*)d_in[0];
    const float* W_chem = (const float*)d_in[1];
    const float* b_chem = (const float*)d_in[2];
    const float* W_elec = (const float*)d_in[3];
    const float* b_elec = (const float*)d_in[4];
    const float* W_out  = (const float*)d_in[5];
    const float* b_out  = (const float*)d_in[6];
    const int* src_chem = (const int*)d_in[7];
    const int* dst_chem = (const int*)d_in[8];
    const int* src_elec = (const int*)d_in[9];
    const int* dst_elec = (const int*)d_in[10];
    float* out = (float*)d_out;

    const int N = in_sizes[0] / D;  // 50000
    const int E = in_sizes[7];      // 500000

    // ws layout:
    unsigned short* fbf = (unsigned short*)d_ws;        // N*D bf16
    unsigned short* hbf = fbf + (size_t)N * D;          // N*D bf16
    int* cchem   = (int*)(hbf + (size_t)N * D);         // N
    int* cursor  = cchem + N;                           // N
    int* celec   = cursor + N;                          // N
    int* row_ptr = celec + N;                           // N+1 (+pad)
    int* aux     = row_ptr + N + 15;                    // 256
    unsigned short* csr = (unsigned short*)(aux + 256); // E

    // S_c/S_e live in d_out (bf16) until the final GEMM overwrites it
    unsigned short* S_c = (unsigned short*)d_out;
    unsigned short* S_e = S_c + (size_t)N * D;

    const int nscan = (N + 255) / 256;
    const int nedge = (E + 255) / 256;
    const int nagg  = (N + 3) / 4;
    const int n8    = N * D / 8;
    dim3 gg((N + 127) / 128, 2);

    convert_bf<<<(n8 + 255) / 256, 256, 0, stream>>>((const float4*)feats, (uint4*)fbf, n8);

    // ---- chem: CSR build + aggregate (zero covers cchem+cursor, adjacent) ----
    zero_ints<<<(2 * N + 255) / 256, 256, 0, stream>>>(cchem, 2 * N);
    hist_kernel<<<nedge, 256, 0, stream>>>(dst_chem, cchem, E);
    scan_block<<<nscan, 256, 0, stream>>>(cchem, row_ptr, aux, N);
    scan_aux<<<1, 256, 0, stream>>>(aux, nscan);
    scan_add<<<nscan, 256, 0, stream>>>(row_ptr, aux, cchem, N);
    fill_csr<<<nedge, 256, 0, stream>>>(src_chem, dst_chem, row_ptr, cursor, csr, E);
    aggregate_bf<<<nagg, 256, 0, stream>>>(fbf, csr, row_ptr, S_c, N);

    // ---- elec (zero covers cursor+celec, adjacent) ----
    zero_ints<<<(2 * N + 255) / 256, 256, 0, stream>>>(cursor, 2 * N);
    hist_kernel<<<nedge, 256, 0, stream>>>(dst_elec, celec, E);
    scan_block<<<nscan, 256, 0, stream>>>(celec, row_ptr, aux, N);
    scan_aux<<<1, 256, 0, stream>>>(aux, nscan);
    scan_add<<<nscan, 256, 0, stream>>>(row_ptr, aux, celec, N);
    fill_csr<<<nedge, 256, 0, stream>>>(src_elec, dst_elec, row_ptr, cursor, csr, E);
    aggregate_bf<<<nagg, 256, 0, stream>>>(fbf, csr, row_ptr, S_e, N);

    // ---- fused MFMA GEMMs ----
    gemm_dual<true, true><<<gg, 256, 0, stream>>>(
        S_c, S_e, W_chem, W_elec, b_chem, b_elec, cchem, celec, hbf, N);
    gemm_dual<false, false><<<gg, 256, 0, stream>>>(
        hbf, fbf, W_out, W_elec, b_out, b_elec, nullptr, nullptr, out, N);
}

// Round 7
// 297.427 us; speedup vs baseline: 19.8572x; 1.2137x over previous
//
#include <hip/hip_runtime.h>

#define D 128

typedef __attribute__((ext_vector_type(8))) short bf16x8;   // 8 bf16 in 4 VGPRs
typedef __attribute__((ext_vector_type(4))) float f32x4;

__device__ __forceinline__ unsigned short f2bf(float x) {
    unsigned int u = __float_as_uint(x);
    u += 0x7fffu + ((u >> 16) & 1u);   // round-to-nearest-even
    return (unsigned short)(u >> 16);
}
__device__ __forceinline__ unsigned int pk2(float lo, float hi) {
    return ((unsigned int)f2bf(hi) << 16) | (unsigned int)f2bf(lo);
}

// ============================ small utilities ==============================

__global__ __launch_bounds__(256) void zero_ints(int* __restrict__ p, int n) {
    int i = blockIdx.x * 256 + threadIdx.x;
    if (i < n) p[i] = 0;
}

// feats fp32 -> bf16 (8 elems/thread)
__global__ __launch_bounds__(256) void convert_bf(const float4* __restrict__ f,
                                                  uint4* __restrict__ o, int n8) {
    int i = blockIdx.x * 256 + threadIdx.x;
    if (i < n8) {
        float4 a = f[2 * i];
        float4 b = f[2 * i + 1];
        o[i] = make_uint4(pk2(a.x, a.y), pk2(a.z, a.w), pk2(b.x, b.y), pk2(b.z, b.w));
    }
}

// combined 2-etype histogram: c[dst_chem[e]]++, c[N + dst_elec[e]]++
__global__ __launch_bounds__(256) void hist2(const int* __restrict__ dc,
                                             const int* __restrict__ de,
                                             int* __restrict__ c, int E, int N) {
    int e = blockIdx.x * 256 + threadIdx.x;
    if (e < 2 * E) {
        int d = (e < E) ? dc[e] : (de[e - E] + N);
        atomicAdd(&c[d], 1);
    }
}

// per-block exclusive scan of c -> row_ptr, block totals -> aux
__global__ __launch_bounds__(256) void scan_block(const int* __restrict__ c,
                                                  int* __restrict__ row_ptr,
                                                  int* __restrict__ aux, int n) {
    __shared__ int sd[256];
    const int t = threadIdx.x;
    const int i = blockIdx.x * 256 + t;
    int x = (i < n) ? c[i] : 0;
    sd[t] = x;
    __syncthreads();
#pragma unroll
    for (int off = 1; off < 256; off <<= 1) {
        int y = (t >= off) ? sd[t - off] : 0;
        __syncthreads();
        sd[t] += y;
        __syncthreads();
    }
    if (i < n) row_ptr[i] = sd[t] - x;  // exclusive
    if (t == 255) aux[blockIdx.x] = sd[255];
}

// exclusive scan of aux in place (nb <= 512), single block
__global__ __launch_bounds__(512) void scan_aux(int* __restrict__ aux, int nb) {
    __shared__ int sd[512];
    const int t = threadIdx.x;
    int x = (t < nb) ? aux[t] : 0;
    sd[t] = x;
    __syncthreads();
#pragma unroll
    for (int off = 1; off < 512; off <<= 1) {
        int y = (t >= off) ? sd[t - off] : 0;
        __syncthreads();
        sd[t] += y;
        __syncthreads();
    }
    if (t < nb) aux[t] = sd[t] - x;
}

__global__ __launch_bounds__(256) void scan_add(int* __restrict__ row_ptr,
                                                const int* __restrict__ aux,
                                                const int* __restrict__ c, int n) {
    int i = blockIdx.x * 256 + threadIdx.x;
    if (i < n) {
        int r = row_ptr[i] + aux[blockIdx.x];
        row_ptr[i] = r;
        if (i == n - 1) row_ptr[n] = r + c[i];
    }
}

// combined fill: csr[row_ptr[d] + pos] = src  (u16 node ids, N < 65536)
__global__ __launch_bounds__(256) void fill2(const int* __restrict__ sc,
                                             const int* __restrict__ dc,
                                             const int* __restrict__ se,
                                             const int* __restrict__ de,
                                             const int* __restrict__ row_ptr,
                                             int* __restrict__ cursor,
                                             unsigned short* __restrict__ csr,
                                             int E, int N) {
    int e = blockIdx.x * 256 + threadIdx.x;
    if (e < 2 * E) {
        int d, s;
        if (e < E) { d = dc[e];     s = sc[e]; }
        else       { d = de[e - E] + N; s = se[e - E]; }
        int pos = atomicAdd(&cursor[d], 1);
        csr[row_ptr[d] + pos] = (unsigned short)s;
    }
}

// S[v] = sum of bf16 feats rows over in-edges; fp32 accumulate, bf16 store.
// One wave per (node,etype) row of the combined 2N-segment CSR; 4 B/lane ->
// 256 B coalesced gather per edge. Edge loop unrolled x4 with independent
// accumulators: 4 outstanding gathers/wave (R6: 1 at a time -> latency-bound,
// VALUBusy 14.6%, HBM 15%). 1024-thr blocks (16 waves) for occupancy.
__global__ __launch_bounds__(1024) void aggregate_bf(const unsigned short* __restrict__ fbf,
                                                     const unsigned short* __restrict__ csr,
                                                     const int* __restrict__ row_ptr,
                                                     unsigned short* __restrict__ S, int N2) {
    const int v    = blockIdx.x * 16 + (threadIdx.x >> 6);
    const int lane = threadIdx.x & 63;
    if (v < N2) {
        const int beg = row_ptr[v];
        const int end = row_ptr[v + 1];
        const int l2  = lane * 2;
        float sx0 = 0.f, sy0 = 0.f, sx1 = 0.f, sy1 = 0.f;
        float sx2 = 0.f, sy2 = 0.f, sx3 = 0.f, sy3 = 0.f;
        int e = beg;
        for (; e + 4 <= end; e += 4) {
            int s0 = csr[e + 0];
            int s1 = csr[e + 1];
            int s2 = csr[e + 2];
            int s3 = csr[e + 3];
            unsigned int u0 = *(const unsigned int*)(fbf + (size_t)s0 * D + l2);
            unsigned int u1 = *(const unsigned int*)(fbf + (size_t)s1 * D + l2);
            unsigned int u2 = *(const unsigned int*)(fbf + (size_t)s2 * D + l2);
            unsigned int u3 = *(const unsigned int*)(fbf + (size_t)s3 * D + l2);
            sx0 += __uint_as_float(u0 << 16);
            sy0 += __uint_as_float(u0 & 0xffff0000u);
            sx1 += __uint_as_float(u1 << 16);
            sy1 += __uint_as_float(u1 & 0xffff0000u);
            sx2 += __uint_as_float(u2 << 16);
            sy2 += __uint_as_float(u2 & 0xffff0000u);
            sx3 += __uint_as_float(u3 << 16);
            sy3 += __uint_as_float(u3 & 0xffff0000u);
        }
        for (; e < end; ++e) {
            int sv = csr[e];
            unsigned int u = *(const unsigned int*)(fbf + (size_t)sv * D + l2);
            sx0 += __uint_as_float(u << 16);
            sy0 += __uint_as_float(u & 0xffff0000u);
        }
        float sx = (sx0 + sx1) + (sx2 + sx3);
        float sy = (sy0 + sy1) + (sy2 + sy3);
        *(unsigned int*)(S + (size_t)v * D + l2) =
            ((unsigned int)f2bf(sy) << 16) | (unsigned int)f2bf(sx);
    }
}

// ============================ MFMA dual GEMM ===============================
// out[r][j] = sum_k A1[r][k]*W1[j][k] + sum_k A2[r][k]*W2[j][k] + bias(r,j)
// (unchanged from R6 — verified correct, absmax 0.0625)
template <bool DEG, bool OUT_BF16>
__global__ __launch_bounds__(256, 2) void gemm_dual(
    const unsigned short* __restrict__ A1, const unsigned short* __restrict__ A2,
    const float* __restrict__ W1, const float* __restrict__ W2,
    const float* __restrict__ bias1, const float* __restrict__ bias2,
    const int* __restrict__ deg1, const int* __restrict__ deg2,
    void* outp, int M) {
    __shared__ unsigned int Wt[64 * 128];   // 64 n-rows x 256 k (bf16 pairs)
    __shared__ unsigned int At[128 * 64];   // 128 m-rows x 128 k (bf16 pairs)
    const int t  = threadIdx.x;
    const int r0 = blockIdx.x * 128;
    const int nb = blockIdx.y * 64;

#pragma unroll
    for (int i = 0; i < 8; ++i) {
        int g  = i * 256 + t;
        int j  = g >> 5;
        int cc = g & 31;
        int k  = cc * 8;
        const float* row = (k < 128) ? (W1 + (nb + j) * 128 + k)
                                     : (W2 + (nb + j) * 128 + (k - 128));
        float4 w0 = *(const float4*)(row);
        float4 w1 = *(const float4*)(row + 4);
        *(uint4*)(Wt + j * 128 + ((cc ^ (j & 7)) << 2)) =
            make_uint4(pk2(w0.x, w0.y), pk2(w0.z, w0.w), pk2(w1.x, w1.y), pk2(w1.z, w1.w));
    }
#define STAGE_A(AB)                                                             \
    {                                                                           \
        _Pragma("unroll") for (int i = 0; i < 8; ++i) {                         \
            int g  = i * 256 + t;                                               \
            int m  = g >> 4;                                                    \
            int cc = g & 15;                                                    \
            int r  = r0 + m;                                                    \
            uint4 v = make_uint4(0u, 0u, 0u, 0u);                               \
            if (r < M) v = *(const uint4*)((AB) + (size_t)r * 128 + cc * 8);    \
            *(uint4*)(At + m * 64 + ((cc ^ (m & 7)) << 2)) = v;                 \
        }                                                                       \
    }

    const int w    = t >> 6;
    const int w32  = w * 32;
    const int lane = t & 63;
    const int ln   = lane & 15;
    const int quad = lane >> 4;
    const int lnx  = ln & 7;
    const int rowA0 = (w32 + ln) * 64;
    const int rowA1 = (w32 + 16 + ln) * 64;
    const int rowB0 = (ln) * 128;
    const int rowB1 = (16 + ln) * 128;
    const int rowB2 = (32 + ln) * 128;
    const int rowB3 = (48 + ln) * 128;

    f32x4 acc00 = {0.f, 0.f, 0.f, 0.f}, acc01 = {0.f, 0.f, 0.f, 0.f};
    f32x4 acc02 = {0.f, 0.f, 0.f, 0.f}, acc03 = {0.f, 0.f, 0.f, 0.f};
    f32x4 acc10 = {0.f, 0.f, 0.f, 0.f}, acc11 = {0.f, 0.f, 0.f, 0.f};
    f32x4 acc12 = {0.f, 0.f, 0.f, 0.f}, acc13 = {0.f, 0.f, 0.f, 0.f};

#define KSTEP(KS, HC)                                                                \
    {                                                                                \
        const int ca = ((((KS)*4 + quad) ^ lnx) << 2);                               \
        bf16x8 a0 = *(const bf16x8*)(At + rowA0 + ca);                               \
        bf16x8 a1 = *(const bf16x8*)(At + rowA1 + ca);                               \
        const int cb = ((((HC) + (KS)*4 + quad) ^ lnx) << 2);                        \
        bf16x8 b0v = *(const bf16x8*)(Wt + rowB0 + cb);                              \
        bf16x8 b1v = *(const bf16x8*)(Wt + rowB1 + cb);                              \
        bf16x8 b2v = *(const bf16x8*)(Wt + rowB2 + cb);                              \
        bf16x8 b3v = *(const bf16x8*)(Wt + rowB3 + cb);                              \
        acc00 = __builtin_amdgcn_mfma_f32_16x16x32_bf16(a0, b0v, acc00, 0, 0, 0);    \
        acc01 = __builtin_amdgcn_mfma_f32_16x16x32_bf16(a0, b1v, acc01, 0, 0, 0);    \
        acc02 = __builtin_amdgcn_mfma_f32_16x16x32_bf16(a0, b2v, acc02, 0, 0, 0);    \
        acc03 = __builtin_amdgcn_mfma_f32_16x16x32_bf16(a0, b3v, acc03, 0, 0, 0);    \
        acc10 = __builtin_amdgcn_mfma_f32_16x16x32_bf16(a1, b0v, acc10, 0, 0, 0);    \
        acc11 = __builtin_amdgcn_mfma_f32_16x16x32_bf16(a1, b1v, acc11, 0, 0, 0);    \
        acc12 = __builtin_amdgcn_mfma_f32_16x16x32_bf16(a1, b2v, acc12, 0, 0, 0);    \
        acc13 = __builtin_amdgcn_mfma_f32_16x16x32_bf16(a1, b3v, acc13, 0, 0, 0);    \
    }

    STAGE_A(A1);
    __syncthreads();
    KSTEP(0, 0) KSTEP(1, 0) KSTEP(2, 0) KSTEP(3, 0)
    __syncthreads();
    STAGE_A(A2);
    __syncthreads();
    KSTEP(0, 16) KSTEP(1, 16) KSTEP(2, 16) KSTEP(3, 16)

#define EPI(ACC, MT, NI)                                                            \
    {                                                                               \
        const int col = nb + (NI)*16 + ln;                                          \
        float bc, be;                                                               \
        if (DEG) { bc = bias1[col]; be = bias2[col]; }                              \
        else     { bc = bias1[col] + bias2[col]; be = 0.f; }                        \
        _Pragma("unroll") for (int rg = 0; rg < 4; ++rg) {                          \
            const int rr = r0 + w32 + (MT)*16 + quad * 4 + rg;                      \
            if (rr < M) {                                                           \
                float val = ACC[rg];                                                \
                if (DEG) val += (float)deg1[rr] * bc + (float)deg2[rr] * be;        \
                else     val += bc;                                                 \
                if (OUT_BF16)                                                       \
                    ((unsigned short*)outp)[(size_t)rr * 128 + col] = f2bf(val);    \
                else                                                                \
                    ((float*)outp)[(size_t)rr * 128 + col] = val;                   \
            }                                                                       \
        }                                                                           \
    }
    EPI(acc00, 0, 0) EPI(acc01, 0, 1) EPI(acc02, 0, 2) EPI(acc03, 0, 3)
    EPI(acc10, 1, 0) EPI(acc11, 1, 1) EPI(acc12, 1, 2) EPI(acc13, 1, 3)
#undef EPI
#undef KSTEP
#undef STAGE_A
}

// ============================ driver =======================================
// Combined 2N-segment CSR (elec dst offset +N): one hist/scan/fill/aggregate
// chain for both etypes (launches 17 -> 10). Then, by linearity:
//   h   = S_c@Wc.T + S_e@We.T + deg_c*b_c + deg_e*b_e            [bf16, ws]
//   out = h@Wo.T + fbf@We.T + (b_o + b_e)                        [fp32, d_out]

extern "C" void kernel_launch(void* const* d_in, const int* in_sizes, int n_in,
                              void* d_out, int out_size, void* d_ws, size_t ws_size,
                              hipStream_t stream) {
    const float* feats  = (const float*)d_in[0];
    const float* W_chem = (const float*)d_in[1];
    const float* b_chem = (const float*)d_in[2];
    const float* W_elec = (const float*)d_in[3];
    const float* b_elec = (const float*)d_in[4];
    const float* W_out  = (const float*)d_in[5];
    const float* b_out  = (const float*)d_in[6];
    const int* src_chem = (const int*)d_in[7];
    const int* dst_chem = (const int*)d_in[8];
    const int* src_elec = (const int*)d_in[9];
    const int* dst_elec = (const int*)d_in[10];
    float* out = (float*)d_out;

    const int N = in_sizes[0] / D;  // 50000
    const int E = in_sizes[7];      // 500000
    const int N2 = 2 * N;

    // ws layout:
    unsigned short* fbf = (unsigned short*)d_ws;        // N*D bf16
    unsigned short* hbf = fbf + (size_t)N * D;          // N*D bf16
    int* c       = (int*)(hbf + (size_t)N * D);         // 2N (degrees; chem|elec)
    int* cursor  = c + N2;                              // 2N
    int* row_ptr = cursor + N2;                         // 2N+1 (+pad)
    int* aux     = row_ptr + N2 + 15;                   // 512
    unsigned short* csr = (unsigned short*)(aux + 512); // 2E u16

    // S_c|S_e live contiguously in d_out (bf16) until the final GEMM
    unsigned short* S = (unsigned short*)d_out;         // 2N rows

    const int nscan = (N2 + 255) / 256;                 // 391 (<= 512 for scan_aux)
    const int nedge = (2 * E + 255) / 256;
    const int nagg  = (N2 + 15) / 16;
    const int n8    = N * D / 8;
    dim3 gg((N + 127) / 128, 2);

    convert_bf<<<(n8 + 255) / 256, 256, 0, stream>>>((const float4*)feats, (uint4*)fbf, n8);

    // ---- combined CSR build (c and cursor are adjacent: one zero of 4N) ----
    zero_ints<<<(4 * N + 255) / 256, 256, 0, stream>>>(c, 4 * N);
    hist2<<<nedge, 256, 0, stream>>>(dst_chem, dst_elec, c, E, N);
    scan_block<<<nscan, 256, 0, stream>>>(c, row_ptr, aux, N2);
    scan_aux<<<1, 512, 0, stream>>>(aux, nscan);
    scan_add<<<nscan, 256, 0, stream>>>(row_ptr, aux, c, N2);
    fill2<<<nedge, 256, 0, stream>>>(src_chem, dst_chem, src_elec, dst_elec,
                                     row_ptr, cursor, csr, E, N);
    // ---- pull-aggregate both etypes in one dispatch ----
    aggregate_bf<<<nagg, 1024, 0, stream>>>(fbf, csr, row_ptr, S, N2);

    // ---- fused MFMA GEMMs ----
    gemm_dual<true, true><<<gg, 256, 0, stream>>>(
        S, S + (size_t)N * D, W_chem, W_elec, b_chem, b_elec, c, c + N, hbf, N);
    gemm_dual<false, false><<<gg, 256, 0, stream>>>(
        hbf, fbf, W_out, W_elec, b_out, b_elec, nullptr, nullptr, out, N);
}

// Round 8
// 281.311 us; speedup vs baseline: 20.9947x; 1.0573x over previous
//
#include <hip/hip_runtime.h>

#define D 128

typedef __attribute__((ext_vector_type(8))) short bf16x8;   // 8 bf16 in 4 VGPRs
typedef __attribute__((ext_vector_type(4))) float f32x4;

__device__ __forceinline__ unsigned short f2bf(float x) {
    unsigned int u = __float_as_uint(x);
    u += 0x7fffu + ((u >> 16) & 1u);   // round-to-nearest-even
    return (unsigned short)(u >> 16);
}
__device__ __forceinline__ unsigned int pk2(float lo, float hi) {
    return ((unsigned int)f2bf(hi) << 16) | (unsigned int)f2bf(lo);
}
__device__ __forceinline__ float bf_lo(unsigned int u) { return __uint_as_float(u << 16); }
__device__ __forceinline__ float bf_hi(unsigned int u) { return __uint_as_float(u & 0xffff0000u); }

// ============================ small utilities ==============================

__global__ __launch_bounds__(256) void zero_ints(int* __restrict__ p, int n) {
    int i = blockIdx.x * 256 + threadIdx.x;
    if (i < n) p[i] = 0;
}

// fused: feats fp32->bf16 (i < n8) + combined 2-etype degree histogram (i < 2E)
__global__ __launch_bounds__(256) void prep(const float4* __restrict__ f,
                                            uint4* __restrict__ o, int n8,
                                            const int* __restrict__ dc,
                                            const int* __restrict__ de,
                                            int* __restrict__ c, int E, int N) {
    int i = blockIdx.x * 256 + threadIdx.x;
    if (i < n8) {
        float4 a = f[2 * i];
        float4 b = f[2 * i + 1];
        o[i] = make_uint4(pk2(a.x, a.y), pk2(a.z, a.w), pk2(b.x, b.y), pk2(b.z, b.w));
    }
    if (i < 2 * E) {
        int d = (i < E) ? dc[i] : (de[i - E] + N);
        atomicAdd(&c[d], 1);
    }
}

// per-block exclusive scan of c -> row_ptr, block totals -> aux
__global__ __launch_bounds__(256) void scan_block(const int* __restrict__ c,
                                                  int* __restrict__ row_ptr,
                                                  int* __restrict__ aux, int n) {
    __shared__ int sd[256];
    const int t = threadIdx.x;
    const int i = blockIdx.x * 256 + t;
    int x = (i < n) ? c[i] : 0;
    sd[t] = x;
    __syncthreads();
#pragma unroll
    for (int off = 1; off < 256; off <<= 1) {
        int y = (t >= off) ? sd[t - off] : 0;
        __syncthreads();
        sd[t] += y;
        __syncthreads();
    }
    if (i < n) row_ptr[i] = sd[t] - x;  // exclusive
    if (t == 255) aux[blockIdx.x] = sd[255];
}

// row_ptr[i] += sum(aux[0..blockIdx)) computed in-block (aux <= 512 entries);
// also seeds cursor = row_ptr (absolute CSR indices for fill) and row_ptr[n].
__global__ __launch_bounds__(256) void scan_add(int* __restrict__ row_ptr,
                                                const int* __restrict__ aux,
                                                const int* __restrict__ c,
                                                int* __restrict__ cursor, int n) {
    __shared__ int red[256];
    const int t = threadIdx.x;
    const int b = blockIdx.x;
    int acc = 0;
    for (int j = t; j < b; j += 256) acc += aux[j];
    red[t] = acc;
    __syncthreads();
#pragma unroll
    for (int off = 128; off > 0; off >>= 1) {
        if (t < off) red[t] += red[t + off];
        __syncthreads();
    }
    const int base = red[0];
    int i = b * 256 + t;
    if (i < n) {
        int r = row_ptr[i] + base;
        row_ptr[i] = r;
        cursor[i]  = r;
        if (i == n - 1) row_ptr[n] = r + c[i];
    }
}

// combined fill: csr[atomic cursor[d]++] = src  (cursor holds absolute index)
__global__ __launch_bounds__(256) void fill2(const int* __restrict__ sc,
                                             const int* __restrict__ dc,
                                             const int* __restrict__ se,
                                             const int* __restrict__ de,
                                             int* __restrict__ cursor,
                                             unsigned short* __restrict__ csr,
                                             int E, int N) {
    int e = blockIdx.x * 256 + threadIdx.x;
    if (e < 2 * E) {
        int d, s;
        if (e < E) { d = dc[e];         s = sc[e]; }
        else       { d = de[e - E] + N; s = se[e - E]; }
        int idx = atomicAdd(&cursor[d], 1);
        csr[idx] = (unsigned short)s;
    }
}

// S[v] = sum of bf16 feats rows over in-edges; fp32 accumulate, bf16 store.
// 2 rows per wave: 32 lanes x dwordx2 (8 B) per row -> half the gather
// instructions of R7's 64x4B; unroll x4 -> 8 outstanding loads per wave.
// 1024-thr blocks (16 waves, 32 rows).
__global__ __launch_bounds__(1024) void aggregate_bf(const unsigned short* __restrict__ fbf,
                                                     const unsigned short* __restrict__ csr,
                                                     const int* __restrict__ row_ptr,
                                                     unsigned short* __restrict__ S, int N2) {
    const int v   = blockIdx.x * 32 + ((threadIdx.x >> 6) << 1) + ((threadIdx.x >> 5) & 1);
    const int l32 = threadIdx.x & 31;
    if (v < N2) {
        const int beg = row_ptr[v];
        const int end = row_ptr[v + 1];
        const int off = l32 * 4;  // bf16 index within row (4 bf16 = 8 B per lane)
        float4 s0 = make_float4(0.f, 0.f, 0.f, 0.f);
        float4 s1 = make_float4(0.f, 0.f, 0.f, 0.f);
        float4 s2 = make_float4(0.f, 0.f, 0.f, 0.f);
        float4 s3 = make_float4(0.f, 0.f, 0.f, 0.f);
#define ACCUM(U, SA)                  \
        SA.x += bf_lo(U.x);           \
        SA.y += bf_hi(U.x);           \
        SA.z += bf_lo(U.y);           \
        SA.w += bf_hi(U.y);
        int e = beg;
        for (; e + 4 <= end; e += 4) {
            int i0 = csr[e + 0];
            int i1 = csr[e + 1];
            int i2 = csr[e + 2];
            int i3 = csr[e + 3];
            uint2 u0 = *(const uint2*)(fbf + (size_t)i0 * D + off);
            uint2 u1 = *(const uint2*)(fbf + (size_t)i1 * D + off);
            uint2 u2 = *(const uint2*)(fbf + (size_t)i2 * D + off);
            uint2 u3 = *(const uint2*)(fbf + (size_t)i3 * D + off);
            ACCUM(u0, s0) ACCUM(u1, s1) ACCUM(u2, s2) ACCUM(u3, s3)
        }
        for (; e < end; ++e) {
            int sv = csr[e];
            uint2 u = *(const uint2*)(fbf + (size_t)sv * D + off);
            ACCUM(u, s0)
        }
#undef ACCUM
        s0.x += s1.x + s2.x + s3.x;
        s0.y += s1.y + s2.y + s3.y;
        s0.z += s1.z + s2.z + s3.z;
        s0.w += s1.w + s2.w + s3.w;
        uint2 o;
        o.x = pk2(s0.x, s0.y);
        o.y = pk2(s0.z, s0.w);
        *(uint2*)(S + (size_t)v * D + off) = o;
    }
}

// ============================ MFMA dual GEMM ===============================
// out[r][j] = sum_k A1[r][k]*W1[j][k] + sum_k A2[r][k]*W2[j][k] + bias(r,j)
// (unchanged since R6 — verified, absmax 0.0625)
template <bool DEG, bool OUT_BF16>
__global__ __launch_bounds__(256, 2) void gemm_dual(
    const unsigned short* __restrict__ A1, const unsigned short* __restrict__ A2,
    const float* __restrict__ W1, const float* __restrict__ W2,
    const float* __restrict__ bias1, const float* __restrict__ bias2,
    const int* __restrict__ deg1, const int* __restrict__ deg2,
    void* outp, int M) {
    __shared__ unsigned int Wt[64 * 128];   // 64 n-rows x 256 k (bf16 pairs)
    __shared__ unsigned int At[128 * 64];   // 128 m-rows x 128 k (bf16 pairs)
    const int t  = threadIdx.x;
    const int r0 = blockIdx.x * 128;
    const int nb = blockIdx.y * 64;

#pragma unroll
    for (int i = 0; i < 8; ++i) {
        int g  = i * 256 + t;
        int j  = g >> 5;
        int cc = g & 31;
        int k  = cc * 8;
        const float* row = (k < 128) ? (W1 + (nb + j) * 128 + k)
                                     : (W2 + (nb + j) * 128 + (k - 128));
        float4 w0 = *(const float4*)(row);
        float4 w1 = *(const float4*)(row + 4);
        *(uint4*)(Wt + j * 128 + ((cc ^ (j & 7)) << 2)) =
            make_uint4(pk2(w0.x, w0.y), pk2(w0.z, w0.w), pk2(w1.x, w1.y), pk2(w1.z, w1.w));
    }
#define STAGE_A(AB)                                                             \
    {                                                                           \
        _Pragma("unroll") for (int i = 0; i < 8; ++i) {                         \
            int g  = i * 256 + t;                                               \
            int m  = g >> 4;                                                    \
            int cc = g & 15;                                                    \
            int r  = r0 + m;                                                    \
            uint4 v = make_uint4(0u, 0u, 0u, 0u);                               \
            if (r < M) v = *(const uint4*)((AB) + (size_t)r * 128 + cc * 8);    \
            *(uint4*)(At + m * 64 + ((cc ^ (m & 7)) << 2)) = v;                 \
        }                                                                       \
    }

    const int w    = t >> 6;
    const int w32  = w * 32;
    const int lane = t & 63;
    const int ln   = lane & 15;
    const int quad = lane >> 4;
    const int lnx  = ln & 7;
    const int rowA0 = (w32 + ln) * 64;
    const int rowA1 = (w32 + 16 + ln) * 64;
    const int rowB0 = (ln) * 128;
    const int rowB1 = (16 + ln) * 128;
    const int rowB2 = (32 + ln) * 128;
    const int rowB3 = (48 + ln) * 128;

    f32x4 acc00 = {0.f, 0.f, 0.f, 0.f}, acc01 = {0.f, 0.f, 0.f, 0.f};
    f32x4 acc02 = {0.f, 0.f, 0.f, 0.f}, acc03 = {0.f, 0.f, 0.f, 0.f};
    f32x4 acc10 = {0.f, 0.f, 0.f, 0.f}, acc11 = {0.f, 0.f, 0.f, 0.f};
    f32x4 acc12 = {0.f, 0.f, 0.f, 0.f}, acc13 = {0.f, 0.f, 0.f, 0.f};

#define KSTEP(KS, HC)                                                                \
    {                                                                                \
        const int ca = ((((KS)*4 + quad) ^ lnx) << 2);                               \
        bf16x8 a0 = *(const bf16x8*)(At + rowA0 + ca);                               \
        bf16x8 a1 = *(const bf16x8*)(At + rowA1 + ca);                               \
        const int cb = ((((HC) + (KS)*4 + quad) ^ lnx) << 2);                        \
        bf16x8 b0v = *(const bf16x8*)(Wt + rowB0 + cb);                              \
        bf16x8 b1v = *(const bf16x8*)(Wt + rowB1 + cb);                              \
        bf16x8 b2v = *(const bf16x8*)(Wt + rowB2 + cb);                              \
        bf16x8 b3v = *(const bf16x8*)(Wt + rowB3 + cb);                              \
        acc00 = __builtin_amdgcn_mfma_f32_16x16x32_bf16(a0, b0v, acc00, 0, 0, 0);    \
        acc01 = __builtin_amdgcn_mfma_f32_16x16x32_bf16(a0, b1v, acc01, 0, 0, 0);    \
        acc02 = __builtin_amdgcn_mfma_f32_16x16x32_bf16(a0, b2v, acc02, 0, 0, 0);    \
        acc03 = __builtin_amdgcn_mfma_f32_16x16x32_bf16(a0, b3v, acc03, 0, 0, 0);    \
        acc10 = __builtin_amdgcn_mfma_f32_16x16x32_bf16(a1, b0v, acc10, 0, 0, 0);    \
        acc11 = __builtin_amdgcn_mfma_f32_16x16x32_bf16(a1, b1v, acc11, 0, 0, 0);    \
        acc12 = __builtin_amdgcn_mfma_f32_16x16x32_bf16(a1, b2v, acc12, 0, 0, 0);    \
        acc13 = __builtin_amdgcn_mfma_f32_16x16x32_bf16(a1, b3v, acc13, 0, 0, 0);    \
    }

    STAGE_A(A1);
    __syncthreads();
    KSTEP(0, 0) KSTEP(1, 0) KSTEP(2, 0) KSTEP(3, 0)
    __syncthreads();
    STAGE_A(A2);
    __syncthreads();
    KSTEP(0, 16) KSTEP(1, 16) KSTEP(2, 16) KSTEP(3, 16)

#define EPI(ACC, MT, NI)                                                            \
    {                                                                               \
        const int col = nb + (NI)*16 + ln;                                          \
        float bc, be;                                                               \
        if (DEG) { bc = bias1[col]; be = bias2[col]; }                              \
        else     { bc = bias1[col] + bias2[col]; be = 0.f; }                        \
        _Pragma("unroll") for (int rg = 0; rg < 4; ++rg) {                          \
            const int rr = r0 + w32 + (MT)*16 + quad * 4 + rg;                      \
            if (rr < M) {                                                           \
                float val = ACC[rg];                                                \
                if (DEG) val += (float)deg1[rr] * bc + (float)deg2[rr] * be;        \
                else     val += bc;                                                 \
                if (OUT_BF16)                                                       \
                    ((unsigned short*)outp)[(size_t)rr * 128 + col] = f2bf(val);    \
                else                                                                \
                    ((float*)outp)[(size_t)rr * 128 + col] = val;                   \
            }                                                                       \
        }                                                                           \
    }
    EPI(acc00, 0, 0) EPI(acc01, 0, 1) EPI(acc02, 0, 2) EPI(acc03, 0, 3)
    EPI(acc10, 1, 0) EPI(acc11, 1, 1) EPI(acc12, 1, 2) EPI(acc13, 1, 3)
#undef EPI
#undef KSTEP
#undef STAGE_A
}

// ============================ driver =======================================
// 2N-segment CSR (elec dst offset +N), 8 launches total. By linearity:
//   h   = S_c@Wc.T + S_e@We.T + deg_c*b_c + deg_e*b_e            [bf16, ws]
//   out = h@Wo.T + fbf@We.T + (b_o + b_e)                        [fp32, d_out]

extern "C" void kernel_launch(void* const* d_in, const int* in_sizes, int n_in,
                              void* d_out, int out_size, void* d_ws, size_t ws_size,
                              hipStream_t stream) {
    const float* feats  = (const float*)d_in[0];
    const float* W_chem = (const float*)d_in[1];
    const float* b_chem = (const float*)d_in[2];
    const float* W_elec = (const float*)d_in[3];
    const float* b_elec = (const float*)d_in[4];
    const float* W_out  = (const float*)d_in[5];
    const float* b_out  = (const float*)d_in[6];
    const int* src_chem = (const int*)d_in[7];
    const int* dst_chem = (const int*)d_in[8];
    const int* src_elec = (const int*)d_in[9];
    const int* dst_elec = (const int*)d_in[10];
    float* out = (float*)d_out;

    const int N = in_sizes[0] / D;  // 50000
    const int E = in_sizes[7];      // 500000
    const int N2 = 2 * N;

    // ws layout:
    unsigned short* fbf = (unsigned short*)d_ws;        // N*D bf16
    unsigned short* hbf = fbf + (size_t)N * D;          // N*D bf16
    int* c       = (int*)(hbf + (size_t)N * D);         // 2N (degrees; chem|elec)
    int* cursor  = c + N2;                              // 2N (absolute csr cursor)
    int* row_ptr = cursor + N2;                         // 2N+1 (+pad)
    int* aux     = row_ptr + N2 + 15;                   // 512
    unsigned short* csr = (unsigned short*)(aux + 512); // 2E u16

    // S_c|S_e live contiguously in d_out (bf16) until the final GEMM
    unsigned short* S = (unsigned short*)d_out;         // 2N rows

    const int nscan = (N2 + 255) / 256;                 // 391
    const int nedge = (2 * E + 255) / 256;
    const int nagg  = (N2 + 31) / 32;
    const int n8    = N * D / 8;
    const int nprep = (max(n8, 2 * E) + 255) / 256;
    dim3 gg((N + 127) / 128, 2);

    zero_ints<<<(N2 + 255) / 256, 256, 0, stream>>>(c, N2);
    prep<<<nprep, 256, 0, stream>>>((const float4*)feats, (uint4*)fbf, n8,
                                    dst_chem, dst_elec, c, E, N);
    scan_block<<<nscan, 256, 0, stream>>>(c, row_ptr, aux, N2);
    scan_add<<<nscan, 256, 0, stream>>>(row_ptr, aux, c, cursor, N2);
    fill2<<<nedge, 256, 0, stream>>>(src_chem, dst_chem, src_elec, dst_elec,
                                     cursor, csr, E, N);
    aggregate_bf<<<nagg, 1024, 0, stream>>>(fbf, csr, row_ptr, S, N2);

    gemm_dual<true, true><<<gg, 256, 0, stream>>>(
        S, S + (size_t)N * D, W_chem, W_elec, b_chem, b_elec, c, c + N, hbf, N);
    gemm_dual<false, false><<<gg, 256, 0, stream>>>(
        hbf, fbf, W_out, W_elec, b_out, b_elec, nullptr, nullptr, out, N);
}